// Round 1
// baseline (149.431 us; speedup 1.0000x reference)
//
#include <hip/hip_runtime.h>
#include <math.h>

#define HID 1536
#define NEXP 8
#define NF4 (HID / 4)          // 384 float4 per token row
#define TOK_PER_BLOCK 32       // 4 waves * 8 tokens/wave

// Layout: lane = tid&63; q = lane&7 is the H-slice id, tg = lane>>3 the token
// within the wave. Each lane accumulates 8 expert partial dots over its slice
// (float4 at index k*8+q, k=0..47), then a 3-step xor-butterfly over the
// 8-lane slice group produces full logits on every lane.
__global__ __launch_bounds__(256) void router_topk_kernel(
    const float* __restrict__ hs,
    const float* __restrict__ wgt,
    const float* __restrict__ bias,
    float* __restrict__ out,
    int T)
{
    __shared__ float4 wlds[NEXP * NF4];   // 48 KB: full weight matrix

    const int tid = threadIdx.x;

    // Stage weights global -> LDS, coalesced float4 copy (12 per thread).
    const float4* wg4 = reinterpret_cast<const float4*>(wgt);
    #pragma unroll
    for (int i = 0; i < (NEXP * NF4) / 256; ++i)
        wlds[tid + i * 256] = wg4[tid + i * 256];
    __syncthreads();

    const int lane  = tid & 63;
    const int wid   = tid >> 6;
    const int q     = lane & 7;
    const int tg    = lane >> 3;
    const int token = blockIdx.x * TOK_PER_BLOCK + wid * 8 + tg;

    const float4* hrow = reinterpret_cast<const float4*>(hs) + (size_t)token * NF4;

    float acc[NEXP];
    #pragma unroll
    for (int e = 0; e < NEXP; ++e) acc[e] = 0.0f;

    // 48 float4 per lane, chunked by 8 so ~8 hs loads stay in flight.
    #pragma unroll
    for (int kk = 0; kk < 48; kk += 8) {
        float4 h[8];
        #pragma unroll
        for (int j = 0; j < 8; ++j)
            h[j] = hrow[(kk + j) * 8 + q];
        #pragma unroll
        for (int j = 0; j < 8; ++j) {
            #pragma unroll
            for (int e = 0; e < NEXP; ++e) {
                float4 wv = wlds[e * NF4 + (kk + j) * 8 + q];
                acc[e] = fmaf(h[j].x, wv.x, acc[e]);
                acc[e] = fmaf(h[j].y, wv.y, acc[e]);
                acc[e] = fmaf(h[j].z, wv.z, acc[e]);
                acc[e] = fmaf(h[j].w, wv.w, acc[e]);
            }
        }
    }

    // Reduce across the 8-lane slice group (masks 1,2,4): every lane ends
    // with the full logits of its token.
    #pragma unroll
    for (int m = 1; m <= 4; m <<= 1) {
        #pragma unroll
        for (int e = 0; e < NEXP; ++e)
            acc[e] += __shfl_xor(acc[e], m, 64);
    }

    // scores = sigmoid(logits); choice scores add the correction bias.
    float s[NEXP], sc[NEXP];
    #pragma unroll
    for (int e = 0; e < NEXP; ++e) {
        s[e]  = 1.0f / (1.0f + expf(-acc[e]));
        sc[e] = s[e] + bias[e];
    }

    // top-2 on sc, lowest-index-first tie-break (matches jax.lax.top_k).
    // Track the raw-score weight alongside to avoid runtime-indexed arrays.
    int   i0 = 0;
    float v0 = sc[0], w0 = s[0];
    #pragma unroll
    for (int e = 1; e < NEXP; ++e)
        if (sc[e] > v0) { v0 = sc[e]; w0 = s[e]; i0 = e; }

    int   i1 = -1;
    float v1 = -3.4e38f, w1 = 0.0f;
    #pragma unroll
    for (int e = 0; e < NEXP; ++e)
        if (e != i0 && sc[e] > v1) { v1 = sc[e]; w1 = s[e]; i1 = e; }

    const float inv = 1.0f / (w0 + w1 + 1e-20f);

    if (token < T && q < 2) {
        const float idxv = (q == 0) ? (float)i0 : (float)i1;
        const float wv   = ((q == 0) ? w0 : w1) * inv;
        out[token * 2 + q]         = idxv;   // output 0: indices as f32
        out[T * 2 + token * 2 + q] = wv;     // output 1: normalized weights
    }
}

extern "C" void kernel_launch(void* const* d_in, const int* in_sizes, int n_in,
                              void* d_out, int out_size, void* d_ws, size_t ws_size,
                              hipStream_t stream)
{
    const float* hs   = (const float*)d_in[0];   // (4,4096,1536) f32
    const float* wgt  = (const float*)d_in[1];   // (8,1536) f32
    const float* bias = (const float*)d_in[2];   // (8,) f32
    float* out = (float*)d_out;                  // [2T idx | 2T weights] f32

    const int T = in_sizes[0] / HID;             // 16384
    const int blocks = (T + TOK_PER_BLOCK - 1) / TOK_PER_BLOCK;
    router_topk_kernel<<<blocks, 256, 0, stream>>>(hs, wgt, bias, out, T);
}